// Round 4
// baseline (1268.156 us; speedup 1.0000x reference)
//
#include <hip/hip_runtime.h>
#include <stdint.h>

typedef uint32_t u32;
typedef __attribute__((ext_vector_type(8))) short short8;  // 8 bf16 (4 VGPRs) - MFMA A/B frag
typedef __attribute__((ext_vector_type(4))) float f32x4;   // MFMA C/D frag

#define MREAL 50000
#define NBLK  784        // 8 XCD stripes x 98 blocks x 64 rows = 50176 (>= 50000)

__device__ __forceinline__ float bits2f(u32 b) { float f; __builtin_memcpy(&f, &b, 4); return f; }
__device__ __forceinline__ float bf2f(unsigned short h) { return bits2f(((u32)h) << 16); }
__device__ __forceinline__ unsigned short f2bf(float f) {
    u32 u; __builtin_memcpy(&u, &f, 4);
    u32 r = u + 0x7FFFu + ((u >> 16) & 1u);   // RNE
    return (unsigned short)(r >> 16);
}
__device__ __forceinline__ void addbf8(uint4 v, float a[8]) {
    a[0] += bits2f(v.x << 16); a[1] += bits2f(v.x & 0xFFFF0000u);
    a[2] += bits2f(v.y << 16); a[3] += bits2f(v.y & 0xFFFF0000u);
    a[4] += bits2f(v.z << 16); a[5] += bits2f(v.z & 0xFFFF0000u);
    a[6] += bits2f(v.w << 16); a[7] += bits2f(v.w & 0xFFFF0000u);
}

// ---------------------------------------------------------------------------
// Grid barrier: device-scope (agent) monotonic-counter barrier.
// All 784 blocks are co-resident by construction (launch_bounds(256,4):
// VGPR<=128, LDS 37888<=40960 -> 4 blocks/CU guaranteed -> capacity 1024).
// Release: every thread __threadfence()s its stores, __syncthreads orders
// them before t0's agent-scope RMW. Acquire: t0 agent-acquire spin, then
// block-wide __threadfence() after __syncthreads.
// ---------------------------------------------------------------------------
__device__ __forceinline__ void gsync(unsigned* bar, unsigned target) {
    __threadfence();                     // release my stores to agent scope
    __syncthreads();                     // all block stores ordered before arrive
    if (threadIdx.x == 0) {
        __hip_atomic_fetch_add(bar, 1u, __ATOMIC_RELEASE, __HIP_MEMORY_SCOPE_AGENT);
        while (__hip_atomic_load(bar, __ATOMIC_ACQUIRE, __HIP_MEMORY_SCOPE_AGENT) < target)
            __builtin_amdgcn_s_sleep(2);
    }
    __syncthreads();
    __threadfence();                     // acquire side for all threads
}

// ---------------------------------------------------------------------------
// One fused step: y = [x | neigh_sum] @ [Ws+I ; Wn/6] + (bs+bn); LN; ReLU.
// Round-0 geometry verbatim (best measured: 55.5us/step, FETCH 15.8 MB):
// BM=64 rows/block, 4 waves, each wave 64x64 (4x4 MFMA), barrier-free K-loop,
// burst gather phase first (preserves per-XCD L2 residency of prev step's
// dirty stripe), XCD-striped block->row mapping.
// ---------------------------------------------------------------------------
template <bool OUTF32>
__device__ __forceinline__ void step_body(
    const unsigned short* __restrict__ src,   // x (bf16, 50000x256)
    void* __restrict__ dstv,                  // bf16 or f32, 50000x256
    const unsigned short* __restrict__ Bt,    // this step's [16][256][32] bf16
    const float* __restrict__ b2,             // [256] combined bias (f32)
    const float* __restrict__ lnS,            // [256] ln_scale f32
    const float* __restrict__ lnO,            // [256] ln_offset f32
    const int* __restrict__ nbr,              // [50000][6]
    long r0,
    unsigned short (*AcNm)[264], float* scr, int* ids)
{
    const int t    = threadIdx.x;
    const int wv   = t >> 6;
    const int lane = t & 63;
    const int lo16 = lane & 15;
    const int quad = lane >> 4;

    // ---------- P-1: stage neighbor indices (wave 0; int2 = 8B-aligned) ----------
    if (t < 64) {
        long rc = r0 + t;
        if (rc > MREAL - 1) rc = MREAL - 1;
        const int* nb = nbr + rc * 6;
        int2 a = *(const int2*)nb;
        int2 b = *(const int2*)(nb + 2);
        int2 c = *(const int2*)(nb + 4);
        ids[t * 6 + 0] = a.x; ids[t * 6 + 1] = a.y;
        ids[t * 6 + 2] = b.x; ids[t * 6 + 3] = b.y;
        ids[t * 6 + 4] = c.x; ids[t * 6 + 5] = c.y;
    }
    __syncthreads();

    // ---------- P0: gather neighbor sum, CONTIGUOUS loads (burst phase) ----------
    {
        const int colq = (t & 31) * 8;
        const int rsub = t >> 5;               // 0..7
        #pragma unroll
        for (int it = 0; it < 8; ++it) {
            const int row = it * 8 + rsub;
            const int* idr = ids + row * 6;
            uint4 v0 = *(const uint4*)(src + (long)idr[0] * 256 + colq);
            uint4 v1 = *(const uint4*)(src + (long)idr[1] * 256 + colq);
            uint4 v2 = *(const uint4*)(src + (long)idr[2] * 256 + colq);
            uint4 v3 = *(const uint4*)(src + (long)idr[3] * 256 + colq);
            uint4 v4 = *(const uint4*)(src + (long)idr[4] * 256 + colq);
            uint4 v5 = *(const uint4*)(src + (long)idr[5] * 256 + colq);
            float a[8] = {0, 0, 0, 0, 0, 0, 0, 0};
            addbf8(v0, a); addbf8(v1, a); addbf8(v2, a);
            addbf8(v3, a); addbf8(v4, a); addbf8(v5, a);
            uint4 o;
            o.x = (u32)f2bf(a[0]) | ((u32)f2bf(a[1]) << 16);
            o.y = (u32)f2bf(a[2]) | ((u32)f2bf(a[3]) << 16);
            o.z = (u32)f2bf(a[4]) | ((u32)f2bf(a[5]) << 16);
            o.w = (u32)f2bf(a[6]) | ((u32)f2bf(a[7]) << 16);
            *(uint4*)&AcNm[row][colq] = o;
        }
    }

    // A-row global pointers (clamped for the tail block)
    const unsigned short* aptr[4];
    #pragma unroll
    for (int mf = 0; mf < 4; ++mf) {
        long r = r0 + mf * 16 + lo16;
        if (r >= MREAL) r = MREAL - 1;
        aptr[mf] = src + r * 256 + quad * 8;
    }
    // Per-lane B base: n = wv*64 + nf*16 + lo16; element addr = n*32 + quad*8.
    const unsigned short* bbase = Bt + ((long)(wv * 64 + lo16) * 32 + quad * 8);

    const f32x4 zero4 = {0.f, 0.f, 0.f, 0.f};
    f32x4 acc[4][4];
    #pragma unroll
    for (int mf = 0; mf < 4; ++mf)
        #pragma unroll
        for (int nf = 0; nf < 4; ++nf) acc[mf][nf] = zero4;

    __syncthreads();                                   // AcNm ready

    // ---------- K-loop: barrier-free, fully unrolled (K = 512, 16x32) ----------
    #pragma unroll
    for (int k = 0; k < 16; ++k) {
        short8 afrag[4];
        if (k < 8) {                                   // x-half: global (L2-hot)
            #pragma unroll
            for (int mf = 0; mf < 4; ++mf)
                afrag[mf] = *(const short8*)(aptr[mf] + k * 32);
        } else {                                       // nm-half: LDS
            #pragma unroll
            for (int mf = 0; mf < 4; ++mf)
                afrag[mf] = *(const short8*)&AcNm[mf * 16 + lo16][(k - 8) * 32 + quad * 8];
        }
        short8 bfrag[4];
        #pragma unroll
        for (int nf = 0; nf < 4; ++nf)
            bfrag[nf] = *(const short8*)(bbase + k * 8192 + nf * 512);
        #pragma unroll
        for (int mf = 0; mf < 4; ++mf)
            #pragma unroll
            for (int nf = 0; nf < 4; ++nf)
                acc[mf][nf] = __builtin_amdgcn_mfma_f32_16x16x32_bf16(afrag[mf], bfrag[nf], acc[mf][nf], 0, 0, 0);
    }

    // ---------- Epilogue: bias + LN + ReLU, fully fused ----------
    __syncthreads();                                   // all K-loop AcNm reads done
    float* srp  = scr;                                 // [64][4][2] partial sums
    float* srow = scr + 512;                           // [64][2] mean/rstd

    float biasc[4], gc[4], oc[4];
    #pragma unroll
    for (int nf = 0; nf < 4; ++nf) {
        int col = wv * 64 + nf * 16 + lo16;
        biasc[nf] = b2[col];
        gc[nf] = lnS[col];
        oc[nf] = lnO[col];
    }
    #pragma unroll
    for (int mf = 0; mf < 4; ++mf)
        #pragma unroll
        for (int nf = 0; nf < 4; ++nf) acc[mf][nf] += biasc[nf];

    #pragma unroll
    for (int mf = 0; mf < 4; ++mf) {
        float s1[4], s2[4];
        #pragma unroll
        for (int r = 0; r < 4; ++r) {
            float v0 = acc[mf][0][r], v1 = acc[mf][1][r], v2 = acc[mf][2][r], v3 = acc[mf][3][r];
            s1[r] = v0 + v1 + v2 + v3;
            s2[r] = v0 * v0 + v1 * v1 + v2 * v2 + v3 * v3;
        }
        #pragma unroll
        for (int d = 1; d < 16; d <<= 1) {
            #pragma unroll
            for (int r = 0; r < 4; ++r) {
                s1[r] += __shfl_xor(s1[r], d, 64);
                s2[r] += __shfl_xor(s2[r], d, 64);
            }
        }
        if (lo16 == 0) {
            int row = mf * 16 + quad * 4;
            #pragma unroll
            for (int r = 0; r < 4; ++r) {
                srp[(row + r) * 8 + wv * 2    ] = s1[r];
                srp[(row + r) * 8 + wv * 2 + 1] = s2[r];
            }
        }
    }
    __syncthreads();
    if (t < 64) {
        float S1 = 0.f, S2 = 0.f;
        #pragma unroll
        for (int w = 0; w < 4; ++w) { S1 += srp[t * 8 + w * 2]; S2 += srp[t * 8 + w * 2 + 1]; }
        float mean = S1 * (1.0f / 256.0f);
        float var  = S2 * (1.0f / 256.0f) - mean * mean;
        float rstd = rsqrtf(var + 1e-5f);
        srow[t * 2] = mean; srow[t * 2 + 1] = rstd;
    }
    __syncthreads();

    // Normalize into AcNm (flat [64][256] bf16, global layout) ...
    unsigned short* obuf = &AcNm[0][0];
    #pragma unroll
    for (int mf = 0; mf < 4; ++mf) {
        #pragma unroll
        for (int r = 0; r < 4; ++r) {
            int row = mf * 16 + quad * 4 + r;
            float mean = srow[row * 2], rstd = srow[row * 2 + 1];
            #pragma unroll
            for (int nf = 0; nf < 4; ++nf) {
                float v = (acc[mf][nf][r] - mean) * rstd * gc[nf] + oc[nf];
                v = fmaxf(v, 0.0f);
                obuf[row * 256 + wv * 64 + nf * 16 + lo16] = f2bf(v);
            }
        }
    }
    __syncthreads();

    // ... then store flat & coalesced: 16 B/lane (bf16) or 32 B/lane (f32).
    #pragma unroll
    for (int it = 0; it < 8; ++it) {
        const int e = it * 2048 + t * 8;               // tile element index (8 per lane, one row)
        const long rg = r0 + (e >> 8);
        if (rg < MREAL) {
            uint4 w = *(const uint4*)(obuf + e);
            if (OUTF32) {
                float* dp = (float*)dstv + r0 * 256 + e;
                float4 f0, f1;
                f0.x = bits2f(w.x << 16); f0.y = bits2f(w.x & 0xFFFF0000u);
                f0.z = bits2f(w.y << 16); f0.w = bits2f(w.y & 0xFFFF0000u);
                f1.x = bits2f(w.z << 16); f1.y = bits2f(w.z & 0xFFFF0000u);
                f1.z = bits2f(w.w << 16); f1.w = bits2f(w.w & 0xFFFF0000u);
                *(float4*)dp = f0;
                *(float4*)(dp + 4) = f1;
            } else {
                *(uint4*)((unsigned short*)dstv + r0 * 256 + e) = w;
            }
        }
    }
}

// ---------------------------------------------------------------------------
// MEGAFUSION (round-11): one persistent kernel = cvt + prep + 3 steps with
// device-scope grid barriers. Rounds 1-3 showed the per-step pipeline is at a
// structural plateau (~55us) insensitive to occupancy (24%->44% moved dur
// -5%..+5%), while ~70us (~27%) of total is inter-kernel launch+drain
// overhead (5 dispatches). This removes 4 dispatch boundaries; per-step code,
// phase order, and XCD-striped row mapping are byte-identical to the best
// measured round-0 version, and L2 stripe residency now survives step
// boundaries (no kernel-dispatch cache invalidation between steps).
// ---------------------------------------------------------------------------
__global__ __launch_bounds__(256, 4) void fused_kernel(
    const float* __restrict__ x0,
    float* __restrict__ out,
    const float* __restrict__ Ws, const float* __restrict__ bs,
    const float* __restrict__ Wn, const float* __restrict__ bn,
    const float* __restrict__ lnS, const float* __restrict__ lnO,
    const int* __restrict__ nbr,
    unsigned short* __restrict__ xbf, unsigned short* __restrict__ xA,
    unsigned short* __restrict__ Bt, float* __restrict__ b2,
    unsigned* __restrict__ bar)
{
    __shared__ unsigned short AcNm[64][264];  // nm tile; 528 B stride (odd x16) = bank-uniform
    __shared__ float scr[640];                // LN scratch: srp[512] + srow[128]
    __shared__ int ids[384];                  // 64 rows x 6 neighbor indices

    const int  t    = threadIdx.x;
    const int  b    = blockIdx.x;
    const long gtid = (long)b * 256 + t;

    // ---------- phase 0a: cvt x0 (f32) -> xbf (bf16), grid-strided ----------
    // 12.8M elems = 1.6M groups of 8; 200704 threads -> 8 iterations (tail-guarded).
    for (long g = gtid; g < 1600000; g += (long)NBLK * 256) {
        long i = g * 8;
        float4 a = *(const float4*)(x0 + i);
        float4 bb = *(const float4*)(x0 + i + 4);
        uint4 o;
        o.x = (u32)f2bf(a.x) | ((u32)f2bf(a.y) << 16);
        o.y = (u32)f2bf(a.z) | ((u32)f2bf(a.w) << 16);
        o.z = (u32)f2bf(bb.x) | ((u32)f2bf(bb.y) << 16);
        o.w = (u32)f2bf(bb.z) | ((u32)f2bf(bb.w) << 16);
        *(uint4*)(xbf + i) = o;
    }
    // ---------- phase 0b: prep Bt (bf16 B^T chunk-packed) + b2, grid-strided ----------
    // B = [Ws + I ; Wn/6]; 1/6 mean scale folded into Wn (gather stores SUMS).
    for (long lin = gtid; lin < 393216; lin += (long)NBLK * 256) {
        int kkr = (int)lin & 31;
        int n   = ((int)lin >> 5) & 255;
        int kc  = ((int)lin >> 13) & 15;
        int s   = (int)lin >> 17;
        int kk  = kc * 32 + kkr;
        float v;
        if (kk < 256) v = Ws[(s * 256 + kk) * 256 + n] + (kk == n ? 1.0f : 0.0f);
        else          v = Wn[(s * 256 + (kk - 256)) * 256 + n] * (1.0f / 6.0f);
        Bt[lin] = f2bf(v);
        if (lin < 768) b2[lin] = bs[lin] + bn[lin];
    }

    gsync(bar, NBLK);

    // XCD-stripe mapping: blocks b with b&7==x land on XCD x (round-robin);
    // XCD x owns the contiguous row stripe, so gather stays in its 4 MB L2.
    const long r0 = ((long)(b & 7) * 98 + (b >> 3)) * 64;

    step_body<false>(xbf, (void*)xA, Bt,          b2,       lnS,       lnO,       nbr, r0, AcNm, scr, ids);
    gsync(bar, 2u * NBLK);
    step_body<false>(xA, (void*)xbf, Bt + 131072, b2 + 256, lnS + 256, lnO + 256, nbr, r0, AcNm, scr, ids);
    gsync(bar, 3u * NBLK);
    step_body<true>(xbf, (void*)out, Bt + 262144, b2 + 512, lnS + 512, lnO + 512, nbr, r0, AcNm, scr, ids);
}

// ---------------------------------------------------------------------------
extern "C" void kernel_launch(void* const* d_in, const int* in_sizes, int n_in,
                              void* d_out, int out_size, void* d_ws, size_t ws_size,
                              hipStream_t stream) {
    const float* x0  = (const float*)d_in[0];  // 50000x256 f32
    const float* Ws  = (const float*)d_in[1];  // 3x256x256 f32
    const float* bs  = (const float*)d_in[2];  // 3x256 f32
    const float* Wn  = (const float*)d_in[3];  // 3x256x256 f32
    const float* bn  = (const float*)d_in[4];  // 3x256 f32
    const float* lnS = (const float*)d_in[5];  // 3x256 f32
    const float* lnO = (const float*)d_in[6];  // 3x256 f32
    const int* nbr   = (const int*)d_in[7];    // 50000x6 i32

    char* ws = (char*)d_ws;
    const size_t XBYTES = (size_t)MREAL * 256 * 2;               // 25,600,000 (bf16 state)
    unsigned short* xbf = (unsigned short*)ws;
    unsigned short* xA  = (unsigned short*)(ws + XBYTES);
    unsigned short* Bt  = (unsigned short*)(ws + 2 * XBYTES);    // 786,432 B
    float*          b2  = (float*)(ws + 2 * XBYTES + 786432);    // 3,072 B
    unsigned*       bar = (unsigned*)(ws + 2 * XBYTES + 786432 + 3072);  // 64 B barrier

    hipMemsetAsync(bar, 0, 64, stream);
    fused_kernel<<<NBLK, 256, 0, stream>>>(x0, (float*)d_out, Ws, bs, Wn, bn,
                                           lnS, lnO, nbr, xbf, xA, Bt, b2, bar);
}

// Round 5
// 271.265 us; speedup vs baseline: 4.6750x; 4.6750x over previous
//
#include <hip/hip_runtime.h>
#include <stdint.h>

typedef uint32_t u32;
typedef __attribute__((ext_vector_type(8))) short short8;  // 8 bf16 (4 VGPRs) - MFMA A/B frag
typedef __attribute__((ext_vector_type(4))) float f32x4;   // MFMA C/D frag

#define MREAL 50000
#define NBLK  784        // 8 XCD stripes x 98 blocks x 64 rows = 50176 (>= 50000)

__device__ __forceinline__ float bits2f(u32 b) { float f; __builtin_memcpy(&f, &b, 4); return f; }
__device__ __forceinline__ float bf2f(unsigned short h) { return bits2f(((u32)h) << 16); }
__device__ __forceinline__ unsigned short f2bf(float f) {
    u32 u; __builtin_memcpy(&u, &f, 4);
    u32 r = u + 0x7FFFu + ((u >> 16) & 1u);   // RNE
    return (unsigned short)(r >> 16);
}
__device__ __forceinline__ void addbf8(uint4 v, float a[8]) {
    a[0] += bits2f(v.x << 16); a[1] += bits2f(v.x & 0xFFFF0000u);
    a[2] += bits2f(v.y << 16); a[3] += bits2f(v.y & 0xFFFF0000u);
    a[4] += bits2f(v.z << 16); a[5] += bits2f(v.z & 0xFFFF0000u);
    a[6] += bits2f(v.w << 16); a[7] += bits2f(v.w & 0xFFFF0000u);
}

// ---------------------------------------------------------------------------
// x0 (f32) -> bf16, 8 elements/thread.
// ---------------------------------------------------------------------------
__global__ void cvt_kernel(const float* __restrict__ in, unsigned short* __restrict__ out) {
    long i = ((long)blockIdx.x * 256 + threadIdx.x) * 8;
    float4 a = *(const float4*)(in + i);
    float4 b = *(const float4*)(in + i + 4);
    uint4 o;
    o.x = (u32)f2bf(a.x) | ((u32)f2bf(a.y) << 16);
    o.y = (u32)f2bf(a.z) | ((u32)f2bf(a.w) << 16);
    o.z = (u32)f2bf(b.x) | ((u32)f2bf(b.y) << 16);
    o.w = (u32)f2bf(b.z) | ((u32)f2bf(b.w) << 16);
    *(uint4*)(out + i) = o;
}

// ---------------------------------------------------------------------------
// Prep: Bt[step][kc][n][kkr] = bf16 of B^T chunk-packed, B = [Ws + I ; Wn/6]
// (512x256 per step, f32 inputs).  Also b2 = bs + bn (f32).
// 1/6 neighbor-mean scale folded into Wn (gather stores SUMS).
// ---------------------------------------------------------------------------
__global__ void prep_kernel(const float* __restrict__ Ws,
                            const float* __restrict__ bs,
                            const float* __restrict__ Wn,
                            const float* __restrict__ bn,
                            unsigned short* __restrict__ Bt,
                            float* __restrict__ b2) {
    int lin = blockIdx.x * 256 + threadIdx.x;      // 3*16*256*32 = 393216 total
    int kkr = lin & 31;
    int n   = (lin >> 5) & 255;
    int kc  = (lin >> 13) & 15;
    int s   = lin >> 17;
    int kk  = kc * 32 + kkr;
    float v;
    if (kk < 256) v = Ws[(s * 256 + kk) * 256 + n] + (kk == n ? 1.0f : 0.0f);
    else          v = Wn[(s * 256 + (kk - 256)) * 256 + n] * (1.0f / 6.0f);
    Bt[lin] = f2bf(v);
    if (lin < 768) b2[lin] = bs[lin] + bn[lin];
}

// ---------------------------------------------------------------------------
// One fused step: y = [x | neigh_sum] @ [Ws+I ; Wn/6] + (bs+bn); LN; ReLU.
// BM=64 rows/block, 4 waves, each wave 64x64 (4x4 MFMA).
//
// ROUND-12: round-0 structure verbatim (phase order / burst gather / XCD
// striping preserved -> FETCH 15.8 MB), plus the register fix. Round-0 sat
// at EXACTLY the (256,4) unified-file cap: 64 VGPR + 64 acc-AGPR = 128.
// Zero headroom -> compiler serialized every load->wait->consume chain
// (the measured 70% all-idle). Round-3 proved occupancy is a dead lever
// (24%->44% = null) and the grid only fills 3.06 blocks/CU anyway, so
// launch_bounds(256,3) (cap 170) costs nothing. The freed registers fund:
//   - gather: 2-deep software pipeline (iteration it+1's 6 loads issued
//     before consuming it; latency hides under the ~120-op unpack VALU)
//   - K-loop: 2-deep frag prefetch (af/bf for k+1 load before k's MFMAs)
// Megafusion (round-4) is structurally wrong on this chip: grid-barrier
// fences flush the non-coherent per-XCD L2s (FETCH 48->160 MB); kernel
// dispatch boundaries DON'T flush L2, so separate kernels stay.
// ---------------------------------------------------------------------------
template <bool OUTF32>
__global__ __launch_bounds__(256, 3) void step_kernel(
    const unsigned short* __restrict__ src,   // x (bf16, 50000x256)
    void* __restrict__ dstv,                  // bf16 or f32, 50000x256
    const unsigned short* __restrict__ Bt,    // this step's [16][256][32] bf16
    const float* __restrict__ b2,             // [256] combined bias (f32)
    const float* __restrict__ lnS,            // [256] ln_scale f32
    const float* __restrict__ lnO,            // [256] ln_offset f32
    const int* __restrict__ nbr)              // [50000][6]
{
    __shared__ unsigned short AcNm[64][264];  // nm tile; 528 B stride (odd x16) = bank-uniform
    __shared__ float scr[640];                // LN scratch: srp[512] + srow[128]
    __shared__ int ids[384];                  // 64 rows x 6 neighbor indices

    const int t    = threadIdx.x;
    const int wv   = t >> 6;
    const int lane = t & 63;
    const int lo16 = lane & 15;
    const int quad = lane >> 4;
    // XCD-stripe mapping: blocks b with b&7==x land on XCD x (round-robin);
    // XCD x owns the contiguous row stripe, so gather stays in its 4 MB L2.
    const long r0  = ((long)(blockIdx.x & 7) * 98 + (blockIdx.x >> 3)) * 64;

    // ---------- P-1: stage neighbor indices (wave 0; int2 = 8B-aligned) ----------
    if (t < 64) {
        long rc = r0 + t;
        if (rc > MREAL - 1) rc = MREAL - 1;
        const int* nb = nbr + rc * 6;
        int2 a = *(const int2*)nb;
        int2 b = *(const int2*)(nb + 2);
        int2 c = *(const int2*)(nb + 4);
        ids[t * 6 + 0] = a.x; ids[t * 6 + 1] = a.y;
        ids[t * 6 + 2] = b.x; ids[t * 6 + 3] = b.y;
        ids[t * 6 + 4] = c.x; ids[t * 6 + 5] = c.y;
    }
    __syncthreads();

    // ---------- P0: gather neighbor sum, CONTIGUOUS loads, 2-deep pipeline ----------
    // Half-wave per row: lane (t&31) covers col (t&31)*8 (16 B); t>>5 picks the
    // row within the group of 8. Each wave-load = 2 full rows = 8 cache lines.
    // Iteration it+1's 6 loads are issued BEFORE consuming iteration it, so the
    // ~250-cycle L2 latency hides under the unpack/accumulate VALU chain.
    {
        const int colq = (t & 31) * 8;
        const int rsub = t >> 5;               // 0..7
        uint4 V[2][6];
        {
            const int* idr = ids + rsub * 6;
            #pragma unroll
            for (int j = 0; j < 6; ++j)
                V[0][j] = *(const uint4*)(src + (long)idr[j] * 256 + colq);
        }
        #pragma unroll
        for (int it = 0; it < 8; ++it) {
            const int cur = it & 1, nxt = cur ^ 1;
            if (it < 7) {
                const int* idr = ids + ((it + 1) * 8 + rsub) * 6;
                #pragma unroll
                for (int j = 0; j < 6; ++j)
                    V[nxt][j] = *(const uint4*)(src + (long)idr[j] * 256 + colq);
            }
            float a[8] = {0, 0, 0, 0, 0, 0, 0, 0};
            #pragma unroll
            for (int j = 0; j < 6; ++j) addbf8(V[cur][j], a);
            uint4 o;
            o.x = (u32)f2bf(a[0]) | ((u32)f2bf(a[1]) << 16);
            o.y = (u32)f2bf(a[2]) | ((u32)f2bf(a[3]) << 16);
            o.z = (u32)f2bf(a[4]) | ((u32)f2bf(a[5]) << 16);
            o.w = (u32)f2bf(a[6]) | ((u32)f2bf(a[7]) << 16);
            *(uint4*)&AcNm[it * 8 + rsub][colq] = o;
        }
    }

    // A-row global pointers (clamped for the tail block)
    const unsigned short* aptr[4];
    #pragma unroll
    for (int mf = 0; mf < 4; ++mf) {
        long r = r0 + mf * 16 + lo16;
        if (r >= MREAL) r = MREAL - 1;
        aptr[mf] = src + r * 256 + quad * 8;
    }
    // Per-lane B base: n = wv*64 + nf*16 + lo16; element addr = n*32 + quad*8.
    const unsigned short* bbase = Bt + ((long)(wv * 64 + lo16) * 32 + quad * 8);

    const f32x4 zero4 = {0.f, 0.f, 0.f, 0.f};
    f32x4 acc[4][4];
    #pragma unroll
    for (int mf = 0; mf < 4; ++mf)
        #pragma unroll
        for (int nf = 0; nf < 4; ++nf) acc[mf][nf] = zero4;

    __syncthreads();                                   // AcNm ready

    // ---------- K-loop: barrier-free, fully unrolled, 2-deep frag prefetch ----------
    // (K = 512 as 16 k-steps of 16x16x32). af/bf for k+1 are loaded before
    // k's 16 MFMAs issue; the MFMA block (~16x5 cycles) covers the L2/LDS
    // latency of the prefetch. Frags 2x(16+16) + acc 64 ~= 150 regs < 170 cap.
    {
        short8 af[2][4], bf[2][4];
        #pragma unroll
        for (int mf = 0; mf < 4; ++mf) af[0][mf] = *(const short8*)(aptr[mf]);
        #pragma unroll
        for (int nf = 0; nf < 4; ++nf) bf[0][nf] = *(const short8*)(bbase + nf * 512);
        #pragma unroll
        for (int k = 0; k < 16; ++k) {
            const int cur = k & 1, nxt = cur ^ 1;
            if (k < 15) {
                const int kk = k + 1;
                if (kk < 8) {                          // x-half: global (L2-hot)
                    #pragma unroll
                    for (int mf = 0; mf < 4; ++mf)
                        af[nxt][mf] = *(const short8*)(aptr[mf] + kk * 32);
                } else {                               // nm-half: LDS
                    #pragma unroll
                    for (int mf = 0; mf < 4; ++mf)
                        af[nxt][mf] = *(const short8*)&AcNm[mf * 16 + lo16][(kk - 8) * 32 + quad * 8];
                }
                #pragma unroll
                for (int nf = 0; nf < 4; ++nf)
                    bf[nxt][nf] = *(const short8*)(bbase + kk * 8192 + nf * 512);
            }
            #pragma unroll
            for (int mf = 0; mf < 4; ++mf)
                #pragma unroll
                for (int nf = 0; nf < 4; ++nf)
                    acc[mf][nf] = __builtin_amdgcn_mfma_f32_16x16x32_bf16(af[cur][mf], bf[cur][nf], acc[mf][nf], 0, 0, 0);
        }
    }

    // ---------- Epilogue: bias + LN + ReLU, fully fused ----------
    __syncthreads();                                   // all K-loop AcNm reads done
    float* srp  = scr;                                 // [64][4][2] partial sums
    float* srow = scr + 512;                           // [64][2] mean/rstd

    float biasc[4], gc[4], oc[4];
    #pragma unroll
    for (int nf = 0; nf < 4; ++nf) {
        int col = wv * 64 + nf * 16 + lo16;
        biasc[nf] = b2[col];
        gc[nf] = lnS[col];
        oc[nf] = lnO[col];
    }
    #pragma unroll
    for (int mf = 0; mf < 4; ++mf)
        #pragma unroll
        for (int nf = 0; nf < 4; ++nf) acc[mf][nf] += biasc[nf];

    #pragma unroll
    for (int mf = 0; mf < 4; ++mf) {
        float s1[4], s2[4];
        #pragma unroll
        for (int r = 0; r < 4; ++r) {
            float v0 = acc[mf][0][r], v1 = acc[mf][1][r], v2 = acc[mf][2][r], v3 = acc[mf][3][r];
            s1[r] = v0 + v1 + v2 + v3;
            s2[r] = v0 * v0 + v1 * v1 + v2 * v2 + v3 * v3;
        }
        #pragma unroll
        for (int d = 1; d < 16; d <<= 1) {
            #pragma unroll
            for (int r = 0; r < 4; ++r) {
                s1[r] += __shfl_xor(s1[r], d, 64);
                s2[r] += __shfl_xor(s2[r], d, 64);
            }
        }
        if (lo16 == 0) {
            int row = mf * 16 + quad * 4;
            #pragma unroll
            for (int r = 0; r < 4; ++r) {
                srp[(row + r) * 8 + wv * 2    ] = s1[r];
                srp[(row + r) * 8 + wv * 2 + 1] = s2[r];
            }
        }
    }
    __syncthreads();
    if (t < 64) {
        float S1 = 0.f, S2 = 0.f;
        #pragma unroll
        for (int w = 0; w < 4; ++w) { S1 += srp[t * 8 + w * 2]; S2 += srp[t * 8 + w * 2 + 1]; }
        float mean = S1 * (1.0f / 256.0f);
        float var  = S2 * (1.0f / 256.0f) - mean * mean;
        float rstd = rsqrtf(var + 1e-5f);
        srow[t * 2] = mean; srow[t * 2 + 1] = rstd;
    }
    __syncthreads();

    // Normalize into AcNm (flat [64][256] bf16, global layout) ...
    unsigned short* obuf = &AcNm[0][0];
    #pragma unroll
    for (int mf = 0; mf < 4; ++mf) {
        #pragma unroll
        for (int r = 0; r < 4; ++r) {
            int row = mf * 16 + quad * 4 + r;
            float mean = srow[row * 2], rstd = srow[row * 2 + 1];
            #pragma unroll
            for (int nf = 0; nf < 4; ++nf) {
                float v = (acc[mf][nf][r] - mean) * rstd * gc[nf] + oc[nf];
                v = fmaxf(v, 0.0f);
                obuf[row * 256 + wv * 64 + nf * 16 + lo16] = f2bf(v);
            }
        }
    }
    __syncthreads();

    // ... then store flat & coalesced: 16 B/lane (bf16) or 32 B/lane (f32).
    #pragma unroll
    for (int it = 0; it < 8; ++it) {
        const int e = it * 2048 + t * 8;               // tile element index (8 per lane, one row)
        const long rg = r0 + (e >> 8);
        if (rg < MREAL) {
            uint4 w = *(const uint4*)(obuf + e);
            if (OUTF32) {
                float* dp = (float*)dstv + r0 * 256 + e;
                float4 f0, f1;
                f0.x = bits2f(w.x << 16); f0.y = bits2f(w.x & 0xFFFF0000u);
                f0.z = bits2f(w.y << 16); f0.w = bits2f(w.y & 0xFFFF0000u);
                f1.x = bits2f(w.z << 16); f1.y = bits2f(w.z & 0xFFFF0000u);
                f1.z = bits2f(w.w << 16); f1.w = bits2f(w.w & 0xFFFF0000u);
                *(float4*)dp = f0;
                *(float4*)(dp + 4) = f1;
            } else {
                *(uint4*)((unsigned short*)dstv + r0 * 256 + e) = w;
            }
        }
    }
}

// ---------------------------------------------------------------------------
extern "C" void kernel_launch(void* const* d_in, const int* in_sizes, int n_in,
                              void* d_out, int out_size, void* d_ws, size_t ws_size,
                              hipStream_t stream) {
    const float* x0  = (const float*)d_in[0];  // 50000x256 f32
    const float* Ws  = (const float*)d_in[1];  // 3x256x256 f32
    const float* bs  = (const float*)d_in[2];  // 3x256 f32
    const float* Wn  = (const float*)d_in[3];  // 3x256x256 f32
    const float* bn  = (const float*)d_in[4];  // 3x256 f32
    const float* lnS = (const float*)d_in[5];  // 3x256 f32
    const float* lnO = (const float*)d_in[6];  // 3x256 f32
    const int* nbr   = (const int*)d_in[7];    // 50000x6 i32

    char* ws = (char*)d_ws;
    const size_t XBYTES = (size_t)MREAL * 256 * 2;               // 25,600,000 (bf16 state)
    unsigned short* xbf = (unsigned short*)ws;
    unsigned short* xA  = (unsigned short*)(ws + XBYTES);
    unsigned short* Bt  = (unsigned short*)(ws + 2 * XBYTES);    // 786,432 B
    float*          b2  = (float*)(ws + 2 * XBYTES + 786432);    // 3,072 B

    cvt_kernel <<<6250, 256, 0, stream>>>(x0, xbf);              // 6250*256*8 = 12.8M
    prep_kernel<<<1536, 256, 0, stream>>>(Ws, bs, Wn, bn, Bt, b2);
    step_kernel<false><<<NBLK, 256, 0, stream>>>(xbf, (void*)xA,  Bt,          b2,       lnS,       lnO,       nbr);
    step_kernel<false><<<NBLK, 256, 0, stream>>>(xA,  (void*)xbf, Bt + 131072, b2 + 256, lnS + 256, lnO + 256, nbr);
    step_kernel<true> <<<NBLK, 256, 0, stream>>>(xbf, d_out,      Bt + 262144, b2 + 512, lnS + 512, lnO + 512, nbr);
}

// Round 6
// 231.467 us; speedup vs baseline: 5.4788x; 1.1719x over previous
//
#include <hip/hip_runtime.h>
#include <stdint.h>

typedef uint32_t u32;
typedef __attribute__((ext_vector_type(8))) short short8;  // 8 bf16 (4 VGPRs) - MFMA A/B frag
typedef __attribute__((ext_vector_type(4))) float f32x4;   // MFMA C/D frag

#define MREAL 50000
#define NBLK  784        // 8 XCD stripes x 98 blocks x 64 rows = 50176 (>= 50000)

__device__ __forceinline__ float bits2f(u32 b) { float f; __builtin_memcpy(&f, &b, 4); return f; }
__device__ __forceinline__ float bf2f(unsigned short h) { return bits2f(((u32)h) << 16); }
__device__ __forceinline__ unsigned short f2bf(float f) {
    u32 u; __builtin_memcpy(&u, &f, 4);
    u32 r = u + 0x7FFFu + ((u >> 16) & 1u);   // RNE
    return (unsigned short)(r >> 16);
}
__device__ __forceinline__ void addbf8(uint4 v, float a[8]) {
    a[0] += bits2f(v.x << 16); a[1] += bits2f(v.x & 0xFFFF0000u);
    a[2] += bits2f(v.y << 16); a[3] += bits2f(v.y & 0xFFFF0000u);
    a[4] += bits2f(v.z << 16); a[5] += bits2f(v.z & 0xFFFF0000u);
    a[6] += bits2f(v.w << 16); a[7] += bits2f(v.w & 0xFFFF0000u);
}

// ---------------------------------------------------------------------------
// Merged preprocessing (round-13: one dispatch instead of two; each kernel
// boundary measured ~13us). Blocks [0,6250): x0 f32 -> bf16, 8 elems/thread.
// Blocks [6250,7786): Bt[step][kc][n][kkr] = bf16 B^T chunk-packed,
// B = [Ws + I ; Wn/6] (1/6 mean scale folded into Wn -> gather stores SUMS);
// b2 = bs + bn.
// ---------------------------------------------------------------------------
__global__ void preproc_kernel(const float* __restrict__ x0,
                               const float* __restrict__ Ws,
                               const float* __restrict__ bs,
                               const float* __restrict__ Wn,
                               const float* __restrict__ bn,
                               unsigned short* __restrict__ xbf,
                               unsigned short* __restrict__ Bt,
                               float* __restrict__ b2) {
    const int b = blockIdx.x;
    if (b < 6250) {
        long i = ((long)b * 256 + threadIdx.x) * 8;
        float4 a = *(const float4*)(x0 + i);
        float4 c = *(const float4*)(x0 + i + 4);
        uint4 o;
        o.x = (u32)f2bf(a.x) | ((u32)f2bf(a.y) << 16);
        o.y = (u32)f2bf(a.z) | ((u32)f2bf(a.w) << 16);
        o.z = (u32)f2bf(c.x) | ((u32)f2bf(c.y) << 16);
        o.w = (u32)f2bf(c.z) | ((u32)f2bf(c.w) << 16);
        *(uint4*)(xbf + i) = o;
    } else {
        int lin = (b - 6250) * 256 + threadIdx.x;  // 3*16*256*32 = 393216 total
        int kkr = lin & 31;
        int n   = (lin >> 5) & 255;
        int kc  = (lin >> 13) & 15;
        int s   = lin >> 17;
        int kk  = kc * 32 + kkr;
        float v;
        if (kk < 256) v = Ws[(s * 256 + kk) * 256 + n] + (kk == n ? 1.0f : 0.0f);
        else          v = Wn[(s * 256 + (kk - 256)) * 256 + n] * (1.0f / 6.0f);
        Bt[lin] = f2bf(v);
        if (lin < 768) b2[lin] = bs[lin] + bn[lin];
    }
}

// ---------------------------------------------------------------------------
// One fused step: y = [x | neigh_sum] @ [Ws+I ; Wn/6] + (bs+bn); LN; ReLU.
// BM=64 rows/block, 4 waves, each wave 64x64 (4x4 MFMA).
//
// ROUND-13: round-0 code (proven 55.5us/step; rounds 1/2/3/5 all regressed
// and are reverted) + x-tile LDS staging. Previously all 4 waves loaded
// IDENTICAL A-fragments from global every k-step (8 outstanding L2 loads
// chained by vmcnt before each MFMA bundle; ~200+cyc each). The block's own
// x-tile is 32 KB: stage it into Ax[] during the existing gather burst (one
// extra uint4 load per iteration, same row clamp), making the entire K-loop
// A-side ds_read_b128 (~12cyc) and halving the per-k-step global-load chain
// (B only). Also removes ~12.8 MB/XCD of redundant L2 reads. LDS 37.9->71.7KB
// -> 2 blocks/CU; occupancy is a proven-dead lever (r3: 24->44% = null).
// Megafusion stays dead: grid-barrier fences flush the non-coherent per-XCD
// L2s (r4: FETCH 48->160MB). Explicit SW pipelining stays dead (r5: compiler
// folds it, occupancy drops). Phase ORDER is load-bearing for L2 residency
// (r1: interleave -> FETCH 3.2x).
// ---------------------------------------------------------------------------
template <bool OUTF32>
__global__ __launch_bounds__(256, 2) void step_kernel(
    const unsigned short* __restrict__ src,   // x (bf16, 50000x256)
    void* __restrict__ dstv,                  // bf16 or f32, 50000x256
    const unsigned short* __restrict__ Bt,    // this step's [16][256][32] bf16
    const float* __restrict__ b2,             // [256] combined bias (f32)
    const float* __restrict__ lnS,            // [256] ln_scale f32
    const float* __restrict__ lnO,            // [256] ln_offset f32
    const int* __restrict__ nbr)              // [50000][6]
{
    __shared__ unsigned short Ax[64][264];    // x tile;  528 B stride (odd x16) = bank-spread
    __shared__ unsigned short AcNm[64][264];  // nm tile
    __shared__ float scr[640];                // LN scratch: srp[512] + srow[128]
    __shared__ int ids[384];                  // 64 rows x 6 neighbor indices

    const int t    = threadIdx.x;
    const int wv   = t >> 6;
    const int lane = t & 63;
    const int lo16 = lane & 15;
    const int quad = lane >> 4;
    // XCD-stripe mapping: blocks b with b&7==x land on XCD x (round-robin);
    // XCD x owns the contiguous row stripe, so gather stays in its 4 MB L2.
    const long r0  = ((long)(blockIdx.x & 7) * 98 + (blockIdx.x >> 3)) * 64;

    // ---------- P-1: stage neighbor indices (wave 0; int2 = 8B-aligned) ----------
    if (t < 64) {
        long rc = r0 + t;
        if (rc > MREAL - 1) rc = MREAL - 1;
        const int* nb = nbr + rc * 6;
        int2 a = *(const int2*)nb;
        int2 b = *(const int2*)(nb + 2);
        int2 c = *(const int2*)(nb + 4);
        ids[t * 6 + 0] = a.x; ids[t * 6 + 1] = a.y;
        ids[t * 6 + 2] = b.x; ids[t * 6 + 3] = b.y;
        ids[t * 6 + 4] = c.x; ids[t * 6 + 5] = c.y;
    }
    __syncthreads();

    // ---------- P0: gather neighbor sum + own-row x-tile stage (burst) ----------
    // Half-wave per row: lane (t&31) covers col (t&31)*8 (16 B); t>>5 picks the
    // row within the group of 8. Each wave-load = 2 full rows = 8 cache lines.
    {
        const int colq = (t & 31) * 8;
        const int rsub = t >> 5;               // 0..7
        #pragma unroll
        for (int it = 0; it < 8; ++it) {
            const int row = it * 8 + rsub;
            long rr = r0 + row;                // own row (same clamp as output guard)
            if (rr > MREAL - 1) rr = MREAL - 1;
            uint4 vo = *(const uint4*)(src + rr * 256 + colq);
            const int* idr = ids + row * 6;
            uint4 v0 = *(const uint4*)(src + (long)idr[0] * 256 + colq);
            uint4 v1 = *(const uint4*)(src + (long)idr[1] * 256 + colq);
            uint4 v2 = *(const uint4*)(src + (long)idr[2] * 256 + colq);
            uint4 v3 = *(const uint4*)(src + (long)idr[3] * 256 + colq);
            uint4 v4 = *(const uint4*)(src + (long)idr[4] * 256 + colq);
            uint4 v5 = *(const uint4*)(src + (long)idr[5] * 256 + colq);
            *(uint4*)&Ax[row][colq] = vo;
            float a[8] = {0, 0, 0, 0, 0, 0, 0, 0};
            addbf8(v0, a); addbf8(v1, a); addbf8(v2, a);
            addbf8(v3, a); addbf8(v4, a); addbf8(v5, a);
            uint4 o;
            o.x = (u32)f2bf(a[0]) | ((u32)f2bf(a[1]) << 16);
            o.y = (u32)f2bf(a[2]) | ((u32)f2bf(a[3]) << 16);
            o.z = (u32)f2bf(a[4]) | ((u32)f2bf(a[5]) << 16);
            o.w = (u32)f2bf(a[6]) | ((u32)f2bf(a[7]) << 16);
            *(uint4*)&AcNm[row][colq] = o;
        }
    }

    // Per-lane B base: n = wv*64 + nf*16 + lo16; element addr = n*32 + quad*8.
    const unsigned short* bbase = Bt + ((long)(wv * 64 + lo16) * 32 + quad * 8);

    const f32x4 zero4 = {0.f, 0.f, 0.f, 0.f};
    f32x4 acc[4][4];
    #pragma unroll
    for (int mf = 0; mf < 4; ++mf)
        #pragma unroll
        for (int nf = 0; nf < 4; ++nf) acc[mf][nf] = zero4;

    __syncthreads();                                   // Ax + AcNm ready

    // ---------- K-loop: barrier-free, fully unrolled (K = 512, 16x32) ----------
    // A entirely from LDS (x-half: Ax, nm-half: AcNm); only B from global (L2).
    #pragma unroll
    for (int k = 0; k < 16; ++k) {
        short8 afrag[4];
        if (k < 8) {
            #pragma unroll
            for (int mf = 0; mf < 4; ++mf)
                afrag[mf] = *(const short8*)&Ax[mf * 16 + lo16][k * 32 + quad * 8];
        } else {
            #pragma unroll
            for (int mf = 0; mf < 4; ++mf)
                afrag[mf] = *(const short8*)&AcNm[mf * 16 + lo16][(k - 8) * 32 + quad * 8];
        }
        short8 bfrag[4];
        #pragma unroll
        for (int nf = 0; nf < 4; ++nf)
            bfrag[nf] = *(const short8*)(bbase + k * 8192 + nf * 512);
        #pragma unroll
        for (int mf = 0; mf < 4; ++mf)
            #pragma unroll
            for (int nf = 0; nf < 4; ++nf)
                acc[mf][nf] = __builtin_amdgcn_mfma_f32_16x16x32_bf16(afrag[mf], bfrag[nf], acc[mf][nf], 0, 0, 0);
    }

    // ---------- Epilogue: bias + LN + ReLU, fully fused ----------
    __syncthreads();                                   // all K-loop LDS reads done
    float* srp  = scr;                                 // [64][4][2] partial sums
    float* srow = scr + 512;                           // [64][2] mean/rstd

    float biasc[4], gc[4], oc[4];
    #pragma unroll
    for (int nf = 0; nf < 4; ++nf) {
        int col = wv * 64 + nf * 16 + lo16;
        biasc[nf] = b2[col];
        gc[nf] = lnS[col];
        oc[nf] = lnO[col];
    }
    #pragma unroll
    for (int mf = 0; mf < 4; ++mf)
        #pragma unroll
        for (int nf = 0; nf < 4; ++nf) acc[mf][nf] += biasc[nf];

    #pragma unroll
    for (int mf = 0; mf < 4; ++mf) {
        float s1[4], s2[4];
        #pragma unroll
        for (int r = 0; r < 4; ++r) {
            float v0 = acc[mf][0][r], v1 = acc[mf][1][r], v2 = acc[mf][2][r], v3 = acc[mf][3][r];
            s1[r] = v0 + v1 + v2 + v3;
            s2[r] = v0 * v0 + v1 * v1 + v2 * v2 + v3 * v3;
        }
        #pragma unroll
        for (int d = 1; d < 16; d <<= 1) {
            #pragma unroll
            for (int r = 0; r < 4; ++r) {
                s1[r] += __shfl_xor(s1[r], d, 64);
                s2[r] += __shfl_xor(s2[r], d, 64);
            }
        }
        if (lo16 == 0) {
            int row = mf * 16 + quad * 4;
            #pragma unroll
            for (int r = 0; r < 4; ++r) {
                srp[(row + r) * 8 + wv * 2    ] = s1[r];
                srp[(row + r) * 8 + wv * 2 + 1] = s2[r];
            }
        }
    }
    __syncthreads();
    if (t < 64) {
        float S1 = 0.f, S2 = 0.f;
        #pragma unroll
        for (int w = 0; w < 4; ++w) { S1 += srp[t * 8 + w * 2]; S2 += srp[t * 8 + w * 2 + 1]; }
        float mean = S1 * (1.0f / 256.0f);
        float var  = S2 * (1.0f / 256.0f) - mean * mean;
        float rstd = rsqrtf(var + 1e-5f);
        srow[t * 2] = mean; srow[t * 2 + 1] = rstd;
    }
    __syncthreads();

    // Normalize into AcNm (flat [64][256] bf16, global layout) ...
    unsigned short* obuf = &AcNm[0][0];
    #pragma unroll
    for (int mf = 0; mf < 4; ++mf) {
        #pragma unroll
        for (int r = 0; r < 4; ++r) {
            int row = mf * 16 + quad * 4 + r;
            float mean = srow[row * 2], rstd = srow[row * 2 + 1];
            #pragma unroll
            for (int nf = 0; nf < 4; ++nf) {
                float v = (acc[mf][nf][r] - mean) * rstd * gc[nf] + oc[nf];
                v = fmaxf(v, 0.0f);
                obuf[row * 256 + wv * 64 + nf * 16 + lo16] = f2bf(v);
            }
        }
    }
    __syncthreads();

    // ... then store flat & coalesced: 16 B/lane (bf16) or 32 B/lane (f32).
    #pragma unroll
    for (int it = 0; it < 8; ++it) {
        const int e = it * 2048 + t * 8;               // tile element index (8 per lane, one row)
        const long rg = r0 + (e >> 8);
        if (rg < MREAL) {
            uint4 w = *(const uint4*)(obuf + e);
            if (OUTF32) {
                float* dp = (float*)dstv + r0 * 256 + e;
                float4 f0, f1;
                f0.x = bits2f(w.x << 16); f0.y = bits2f(w.x & 0xFFFF0000u);
                f0.z = bits2f(w.y << 16); f0.w = bits2f(w.y & 0xFFFF0000u);
                f1.x = bits2f(w.z << 16); f1.y = bits2f(w.z & 0xFFFF0000u);
                f1.z = bits2f(w.w << 16); f1.w = bits2f(w.w & 0xFFFF0000u);
                *(float4*)dp = f0;
                *(float4*)(dp + 4) = f1;
            } else {
                *(uint4*)((unsigned short*)dstv + r0 * 256 + e) = w;
            }
        }
    }
}

// ---------------------------------------------------------------------------
extern "C" void kernel_launch(void* const* d_in, const int* in_sizes, int n_in,
                              void* d_out, int out_size, void* d_ws, size_t ws_size,
                              hipStream_t stream) {
    const float* x0  = (const float*)d_in[0];  // 50000x256 f32
    const float* Ws  = (const float*)d_in[1];  // 3x256x256 f32
    const float* bs  = (const float*)d_in[2];  // 3x256 f32
    const float* Wn  = (const float*)d_in[3];  // 3x256x256 f32
    const float* bn  = (const float*)d_in[4];  // 3x256 f32
    const float* lnS = (const float*)d_in[5];  // 3x256 f32
    const float* lnO = (const float*)d_in[6];  // 3x256 f32
    const int* nbr   = (const int*)d_in[7];    // 50000x6 i32

    char* ws = (char*)d_ws;
    const size_t XBYTES = (size_t)MREAL * 256 * 2;               // 25,600,000 (bf16 state)
    unsigned short* xbf = (unsigned short*)ws;
    unsigned short* xA  = (unsigned short*)(ws + XBYTES);
    unsigned short* Bt  = (unsigned short*)(ws + 2 * XBYTES);    // 786,432 B
    float*          b2  = (float*)(ws + 2 * XBYTES + 786432);    // 3,072 B

    preproc_kernel<<<7786, 256, 0, stream>>>(x0, Ws, bs, Wn, bn, xbf, Bt, b2);
    step_kernel<false><<<NBLK, 256, 0, stream>>>(xbf, (void*)xA,  Bt,          b2,       lnS,       lnO,       nbr);
    step_kernel<false><<<NBLK, 256, 0, stream>>>(xA,  (void*)xbf, Bt + 131072, b2 + 256, lnS + 256, lnO + 256, nbr);
    step_kernel<true> <<<NBLK, 256, 0, stream>>>(xbf, d_out,      Bt + 262144, b2 + 512, lnS + 512, lnO + 512, nbr);
}